// Round 3
// baseline (2913.087 us; speedup 1.0000x reference)
//
#include <hip/hip_runtime.h>
#include <cstdint>
#include <cstddef>

// ---------------------------------------------------------------------------
// LSTM T=512 B=64 I=256 H=512  (fp32 in/out, bf16 MFMA compute)
//
// Phase A (prep):    pack Uall bf16, ball=bW+bU (f32), invalidate hbuf tags.
// Phase B (xw_gemm): xw[t*64+b][4H] = x @ Wall^T + ball, bf16 out; x AND W
//                    converted f32->bf16 inline during LDS staging.
// Phase C (scan):    32 persistent WGs = 4 batch-groups(16) x 8 col-slices(64).
//                    Transposed MFMA: A=U (gatecols), B=h^T (batch). Each wave
//                    owns 16 hidden cols x all 4 gates -> f,i,o,c for a cell
//                    live in one lane; no gate exchange, no flags. h handoff
//                    via self-validating tagged 8B slots (tag=t | 2 bf16),
//                    agent-scope relaxed atomics. Raw s_barrier (no vmcnt
//                    drain) keeps prefetches off the critical path.
// ---------------------------------------------------------------------------

typedef __attribute__((ext_vector_type(8))) short short8;
typedef __attribute__((ext_vector_type(4))) float float4v;
typedef __attribute__((ext_vector_type(4))) unsigned int uint4v;

__device__ __forceinline__ unsigned short f2bf(float f) {
  unsigned u = __float_as_uint(f);
  u = u + 0x7FFFu + ((u >> 16) & 1u);   // RNE
  return (unsigned short)(u >> 16);
}
__device__ __forceinline__ float bf2f(unsigned short s) {
  return __uint_as_float(((unsigned)s) << 16);
}
__device__ __forceinline__ unsigned long long pack4(float4 v) {
  return (unsigned long long)f2bf(v.x) |
         ((unsigned long long)f2bf(v.y) << 16) |
         ((unsigned long long)f2bf(v.z) << 32) |
         ((unsigned long long)f2bf(v.w) << 48);
}

// workgroup barrier WITHOUT compiler-inserted s_waitcnt vmcnt(0) drain
__device__ __forceinline__ void barrier_nodrain() {
  asm volatile("s_barrier" ::: "memory");
}
// barrier that only drains LDS ops (ds_write visibility)
__device__ __forceinline__ void barrier_lds() {
  asm volatile("s_waitcnt lgkmcnt(0)\n\ts_barrier" ::: "memory");
}

// ------------------------------ Phase A ------------------------------------
__global__ void prep_kernel(
    const float* __restrict__ Uf, const float* __restrict__ bUf,
    const float* __restrict__ Ui, const float* __restrict__ bUi,
    const float* __restrict__ Uo, const float* __restrict__ bUo,
    const float* __restrict__ Uc, const float* __restrict__ bUc,
    const float* __restrict__ bWf, const float* __restrict__ bWi,
    const float* __restrict__ bWo, const float* __restrict__ bWc,
    unsigned short* __restrict__ Uall, float* __restrict__ ball,
    unsigned long long* __restrict__ hbuf)
{
  const float* Us[4]  = {Uf, Ui, Uo, Uc};
  const float* bWs[4] = {bWf, bWi, bWo, bWc};
  const float* bUs[4] = {bUf, bUi, bUo, bUc};
  const long long NU4 = 262144;   // 2048*512/4
  const long long NB4 = 512;      // 2048/4
  long long idx0 = (long long)blockIdx.x * blockDim.x + threadIdx.x;
  long long stride = (long long)gridDim.x * blockDim.x;
  // invalidate h tag slots (2 parities x 64 rows x 256 slots)
  for (long long u = idx0; u < 32768; u += stride)
    hbuf[u] = 0xFFFFFFFF00000000ull;
  for (long long u = idx0; u < NU4 + NB4; u += stride) {
    if (u < NU4) {
      int e = (int)(u << 2);
      int n = e >> 9, k = e & 511;
      float4 v = *(const float4*)(Us[n >> 9] + (size_t)(n & 511) * 512 + k);
      ((unsigned long long*)Uall)[u] = pack4(v);
    } else {
      long long q = u - NU4;
      int e = (int)(q << 2);
      int gate = e >> 9, r = e & 511;
      float4 a = *(const float4*)(bWs[gate] + r);
      float4 b = *(const float4*)(bUs[gate] + r);
      float4 sv;
      sv.x = a.x + b.x; sv.y = a.y + b.y; sv.z = a.z + b.z; sv.w = a.w + b.w;
      *(float4*)(ball + e) = sv;
    }
  }
}

// ------------------------------ Phase B ------------------------------------
// xw[m][n] = sum_k x[m][k]*W[n][k] + ball[n],  M=32768 N=2048 K=256.
// 128x128 tile, BK=64. Both A (x) and B (W gate) converted f32->bf16 inline.
__global__ __launch_bounds__(256, 2) void xw_gemm(
    const float* __restrict__ x,
    const float* __restrict__ Wf, const float* __restrict__ Wi,
    const float* __restrict__ Wo, const float* __restrict__ Wc,
    const float* __restrict__ ball,
    unsigned short* __restrict__ xw)
{
  __shared__ short As[128 * 72];
  __shared__ short Bs[128 * 72];
  const int tid = threadIdx.x;
  const int bn = blockIdx.x, bm = blockIdx.y;
  const int Mbase = bm * 128, Nbase = bn * 128;
  const int w = tid >> 6, L = tid & 63, lq = L >> 4, lr = L & 15;
  const int wm = w >> 1, wn = w & 1;
  const int srow = tid >> 1, shalf = tid & 1;

  const int gate = bn >> 2;   // 512-wide gates, 4 blocks each
  const float* Wg = gate == 0 ? Wf : gate == 1 ? Wi : gate == 2 ? Wo : Wc;
  const int nrow = (bn & 3) * 128 + srow;

  float4v acc[4][4];
  #pragma unroll
  for (int a = 0; a < 4; ++a)
    #pragma unroll
    for (int b = 0; b < 4; ++b) acc[a][b] = (float4v){0.f, 0.f, 0.f, 0.f};

  for (int ko = 0; ko < 256; ko += 64) {
    const float* gaf = x + (size_t)(Mbase + srow) * 256 + ko + shalf * 32;
    float4 fa[8];
    #pragma unroll
    for (int i = 0; i < 8; ++i) fa[i] = *(const float4*)(gaf + 4 * i);
    const float* gbf = Wg + (size_t)nrow * 256 + ko + shalf * 32;
    float4 fb[8];
    #pragma unroll
    for (int i = 0; i < 8; ++i) fb[i] = *(const float4*)(gbf + 4 * i);
    __syncthreads();  // protect previous iteration's LDS reads
    {
      unsigned long long* pa = (unsigned long long*)&As[srow * 72 + shalf * 32];
      unsigned long long* pb = (unsigned long long*)&Bs[srow * 72 + shalf * 32];
      #pragma unroll
      for (int i = 0; i < 8; ++i) { pa[i] = pack4(fa[i]); pb[i] = pack4(fb[i]); }
    }
    __syncthreads();
    #pragma unroll
    for (int kk = 0; kk < 64; kk += 32) {
      short8 af[4], bfr[4];
      #pragma unroll
      for (int mi = 0; mi < 4; ++mi)
        af[mi] = *(const short8*)&As[(wm * 64 + mi * 16 + lr) * 72 + kk + lq * 8];
      #pragma unroll
      for (int ni = 0; ni < 4; ++ni)
        bfr[ni] = *(const short8*)&Bs[(wn * 64 + ni * 16 + lr) * 72 + kk + lq * 8];
      #pragma unroll
      for (int mi = 0; mi < 4; ++mi)
        #pragma unroll
        for (int ni = 0; ni < 4; ++ni)
          acc[mi][ni] = __builtin_amdgcn_mfma_f32_16x16x32_bf16(
              af[mi], bfr[ni], acc[mi][ni], 0, 0, 0);
    }
  }
  #pragma unroll
  for (int ni = 0; ni < 4; ++ni) {
    int col = Nbase + wn * 64 + ni * 16 + lr;
    float bias = ball[col];
    #pragma unroll
    for (int mi = 0; mi < 4; ++mi) {
      #pragma unroll
      for (int r = 0; r < 4; ++r) {
        int row = Mbase + wm * 64 + mi * 16 + lq * 4 + r;
        xw[(size_t)row * 2048 + col] = f2bf(acc[mi][ni][r] + bias);
      }
    }
  }
}

// ------------------------------ Phase C ------------------------------------
// 32 WGs: g = wg>>3 (16 batch rows), s = wg&7 (64 hidden cols).
// Wave w: 16 cols (s*64+16w..+16), all 4 gates. U A-frags in registers
// (256 VGPR/lane). Lane owns (batch = L&15, 4 cols = +quad*4..+4).
__global__ __launch_bounds__(256, 1) void lstm_scan(
    const unsigned short* __restrict__ xw,
    const unsigned short* __restrict__ Uall,
    unsigned long long* __restrict__ hbuf,   // [2][64][256] tagged slots
    float* __restrict__ out)
{
  __shared__ short hstage[16 * 520];   // h_{t-1}: 16 rows x 512 cols, padded

  const int tid = threadIdx.x;
  const int wg = blockIdx.x;
  const int g = wg >> 3;
  const int s = wg & 7;
  const int w = tid >> 6, L = tid & 63, q = L >> 4, n = L & 15;

  // poll/stage mapping: thread -> (row in group, 16 consecutive slots)
  const int prow = tid & 15;
  const int psb  = (tid >> 4) * 16;    // slot base; cols psb*2..+32

  const int colbase = s * 64 + w * 16 + q * 4;  // 4 gate-cols per lane

  float* hseq = out;
  float* hfin = out + (size_t)512 * 64 * 512;
  float* cfin = hfin + (size_t)64 * 512;

  // U A-fragments, held in registers for all 512 steps.
  // A[m = L&15][k = q*8+j] for tile (gate G, kt): row G*512 + s*64 + w*16 + n
  short8 uf[4][16];
  #pragma unroll
  for (int G = 0; G < 4; ++G)
    #pragma unroll
    for (int kt = 0; kt < 16; ++kt)
      uf[G][kt] = *(const short8*)(Uall +
          (size_t)(G * 512 + s * 64 + w * 16 + n) * 512 + kt * 32 + q * 8);

  // xw register pipeline (one step ahead)
  ushort4 xcur[4], xnxt[4];
  {
    const unsigned short* xp = xw + (size_t)(g * 16 + n) * 2048 + colbase;
    #pragma unroll
    for (int G = 0; G < 4; ++G) xcur[G] = *(const ushort4*)(xp + G * 512);
  }

  float c0 = 0.f, c1 = 0.f, c2 = 0.f, c3 = 0.f;

  for (int t = 0; t < 512; ++t) {
    // issue xw prefetch for t+1 (consumed next iter; never force-drained)
    {
      int tn = (t + 1 < 512) ? (t + 1) : 511;
      const unsigned short* xp =
          xw + (size_t)(tn * 64 + g * 16 + n) * 2048 + colbase;
      #pragma unroll
      for (int G = 0; G < 4; ++G) xnxt[G] = *(const ushort4*)(xp + G * 512);
    }

    float4v acc[4];
    #pragma unroll
    for (int G = 0; G < 4; ++G) acc[G] = (float4v){0.f, 0.f, 0.f, 0.f};

    if (t > 0) {
      // poll own tagged slots (single producer slice per thread)
      const unsigned long long* src = hbuf +
          (size_t)((t - 1) & 1) * 16384 + (size_t)(g * 16 + prow) * 256 + psb;
      unsigned long long v[16];
      for (;;) {
        #pragma unroll
        for (int i = 0; i < 16; ++i)
          v[i] = __hip_atomic_load(&src[i], __ATOMIC_RELAXED,
                                   __HIP_MEMORY_SCOPE_AGENT);
        unsigned bad = 0;
        #pragma unroll
        for (int i = 0; i < 16; ++i)
          bad |= ((unsigned)(v[i] >> 32)) ^ (unsigned)(t - 1);
        if (!bad) break;
        __builtin_amdgcn_s_sleep(1);
      }
      barrier_nodrain();  // join: everyone polled; prior ds_reads long done
      // stage h_{t-1} -> LDS (strip tags, 4B payload per slot)
      #pragma unroll
      for (int j = 0; j < 4; ++j) {
        uint4v pk;
        pk.x = (unsigned)v[4 * j + 0];
        pk.y = (unsigned)v[4 * j + 1];
        pk.z = (unsigned)v[4 * j + 2];
        pk.w = (unsigned)v[4 * j + 3];
        *(uint4v*)((char*)hstage + prow * 1040 + psb * 4 + j * 16) = pk;
      }
      barrier_lds();
      // B-frag: h[batch = n][k = kt*32 + q*8 ..+8]; 4 indep gate chains
      #pragma unroll
      for (int kt = 0; kt < 16; ++kt) {
        short8 hb = *(const short8*)&hstage[n * 520 + kt * 32 + q * 8];
        #pragma unroll
        for (int G = 0; G < 4; ++G)
          acc[G] = __builtin_amdgcn_mfma_f32_16x16x32_bf16(
              uf[G][kt], hb, acc[G], 0, 0, 0);
      }
    }

    // elementwise: lane owns batch n, cols colbase..+4 (r = 0..3)
    float h0, h1, h2, h3;
    {
      const unsigned short* xf = (const unsigned short*)&xcur[0];
      const unsigned short* xi = (const unsigned short*)&xcur[1];
      const unsigned short* xo = (const unsigned short*)&xcur[2];
      const unsigned short* xc = (const unsigned short*)&xcur[3];
      #pragma unroll
      for (int r = 0; r < 4; ++r) {
        float gf = acc[0][r] + bf2f(xf[r]);
        float gi = acc[1][r] + bf2f(xi[r]);
        float go = acc[2][r] + bf2f(xo[r]);
        float gc = acc[3][r] + bf2f(xc[r]);
        float f_ = 1.f / (1.f + __expf(-gf));
        float i_ = 1.f / (1.f + __expf(-gi));
        float o_ = 1.f / (1.f + __expf(-go));
        float ct = 1.f - 2.f / (__expf(2.f * gc) + 1.f);
        float cc = (r == 0 ? c0 : r == 1 ? c1 : r == 2 ? c2 : c3);
        cc = f_ * cc + i_ * ct;
        float hh = o_ * (1.f - 2.f / (__expf(2.f * cc) + 1.f));
        if (r == 0) { c0 = cc; h0 = hh; }
        else if (r == 1) { c1 = cc; h1 = hh; }
        else if (r == 2) { c2 = cc; h2 = hh; }
        else { c3 = cc; h3 = hh; }
      }
    }

    // hseq (nontemporal f32x4)
    size_t orow = (size_t)(t * 64 + g * 16 + n) * 512 + colbase;
    float4v hv4 = {h0, h1, h2, h3};
    __builtin_nontemporal_store(hv4, (float4v*)(hseq + orow));

    // tagged h handoff (self-validating: tag=t | 2 bf16 cols per 8B slot)
    unsigned long long tg = ((unsigned long long)(unsigned)t) << 32;
    unsigned long long s0 =
        tg | (unsigned)(((unsigned)f2bf(h1) << 16) | (unsigned)f2bf(h0));
    unsigned long long s1 =
        tg | (unsigned)(((unsigned)f2bf(h3) << 16) | (unsigned)f2bf(h2));
    unsigned long long* dst = hbuf + (size_t)(t & 1) * 16384 +
        (size_t)(g * 16 + n) * 256 + (colbase >> 1);
    __hip_atomic_store(dst, s0, __ATOMIC_RELAXED, __HIP_MEMORY_SCOPE_AGENT);
    __hip_atomic_store(dst + 1, s1, __ATOMIC_RELAXED, __HIP_MEMORY_SCOPE_AGENT);

    if (t == 511) {
      size_t fo = (size_t)(g * 16 + n) * 512 + colbase;
      *(float4v*)(hfin + fo) = hv4;
      float4v cv4 = {c0, c1, c2, c3};
      *(float4v*)(cfin + fo) = cv4;
    }

    #pragma unroll
    for (int G = 0; G < 4; ++G) xcur[G] = xnxt[G];
  }
}

// ------------------------------ launch -------------------------------------
extern "C" void kernel_launch(void* const* d_in, const int* in_sizes, int n_in,
                              void* d_out, int out_size, void* d_ws, size_t ws_size,
                              hipStream_t stream) {
  (void)in_sizes; (void)n_in; (void)out_size; (void)ws_size;
  const float* x   = (const float*)d_in[0];
  const float* Wf  = (const float*)d_in[1];
  const float* bWf = (const float*)d_in[2];
  const float* Wi  = (const float*)d_in[3];
  const float* bWi = (const float*)d_in[4];
  const float* Wo  = (const float*)d_in[5];
  const float* bWo = (const float*)d_in[6];
  const float* Wc  = (const float*)d_in[7];
  const float* bWc = (const float*)d_in[8];
  const float* Uf  = (const float*)d_in[9];
  const float* bUf = (const float*)d_in[10];
  const float* Ui  = (const float*)d_in[11];
  const float* bUi = (const float*)d_in[12];
  const float* Uo  = (const float*)d_in[13];
  const float* bUo = (const float*)d_in[14];
  const float* Uc  = (const float*)d_in[15];
  const float* bUc = (const float*)d_in[16];

  char* ws = (char*)d_ws;
  unsigned short*     xw   = (unsigned short*)(ws);              // 134217728 B
  unsigned short*     Uall = (unsigned short*)(ws + 134217728);  //   2097152 B
  float*              ball = (float*)         (ws + 136314880);  //      8192 B
  unsigned long long* hbuf = (unsigned long long*)(ws + 136323072); // 262144 B

  prep_kernel<<<512, 256, 0, stream>>>(Uf, bUf, Ui, bUi, Uo, bUo, Uc, bUc,
                                       bWf, bWi, bWo, bWc, Uall, ball, hbuf);
  xw_gemm<<<dim3(16, 256), 256, 0, stream>>>(x, Wf, Wi, Wo, Wc, ball, xw);
  lstm_scan<<<32, 256, 0, stream>>>(xw, Uall, hbuf, (float*)d_out);
}

// Round 4
// 2491.018 us; speedup vs baseline: 1.1694x; 1.1694x over previous
//
#include <hip/hip_runtime.h>
#include <cstdint>
#include <cstddef>

// ---------------------------------------------------------------------------
// LSTM T=512 B=64 I=256 H=512  (fp32 in/out, bf16 MFMA compute)
//
// Phase A (prep):    pack Uall bf16, ball=bW+bU (f32), invalidate hbuf tags.
// Phase B (xw_gemm): xw[t*64+b][4H] = x @ Wall^T + ball, bf16 out.
// Phase C (scan):    128 persistent WGs = 4 batch-groups(16) x 32 col-slices
//                    (16 cols). Wave w = gate w: U rows (gate w, 16 cols) x
//                    K=512 held in EXACTLY 64 VGPRs/lane, pinned with opaque
//                    asm so the allocator cannot re-sink the loads (R2/R3
//                    post-mortem: compiler re-streamed U from L2 every step).
//                    xw folded into MFMA acc init. Tagged 8B h slots (tag=t |
//                    2 bf16) = single store->load sync RT. Two lgkmcnt-only
//                    barriers/step (double-buffered hstage+gates), no vmcnt
//                    drains on the critical path.
// ---------------------------------------------------------------------------

typedef __attribute__((ext_vector_type(8))) short short8;
typedef __attribute__((ext_vector_type(4))) float float4v;
typedef __attribute__((ext_vector_type(4))) unsigned int uint4v;

__device__ __forceinline__ unsigned short f2bf(float f) {
  unsigned u = __float_as_uint(f);
  u = u + 0x7FFFu + ((u >> 16) & 1u);   // RNE
  return (unsigned short)(u >> 16);
}
__device__ __forceinline__ float bf2f(unsigned short s) {
  return __uint_as_float(((unsigned)s) << 16);
}
__device__ __forceinline__ unsigned long long pack4(float4 v) {
  return (unsigned long long)f2bf(v.x) |
         ((unsigned long long)f2bf(v.y) << 16) |
         ((unsigned long long)f2bf(v.z) << 32) |
         ((unsigned long long)f2bf(v.w) << 48);
}

// barrier that only drains LDS ops (ds_write visibility), never vmcnt
__device__ __forceinline__ void barrier_lds() {
  asm volatile("s_waitcnt lgkmcnt(0)\n\ts_barrier" ::: "memory");
}

// ------------------------------ Phase A ------------------------------------
__global__ void prep_kernel(
    const float* __restrict__ Uf, const float* __restrict__ bUf,
    const float* __restrict__ Ui, const float* __restrict__ bUi,
    const float* __restrict__ Uo, const float* __restrict__ bUo,
    const float* __restrict__ Uc, const float* __restrict__ bUc,
    const float* __restrict__ bWf, const float* __restrict__ bWi,
    const float* __restrict__ bWo, const float* __restrict__ bWc,
    unsigned short* __restrict__ Uall, float* __restrict__ ball,
    unsigned long long* __restrict__ hbuf)
{
  const float* Us[4]  = {Uf, Ui, Uo, Uc};
  const float* bWs[4] = {bWf, bWi, bWo, bWc};
  const float* bUs[4] = {bUf, bUi, bUo, bUc};
  const long long NU4 = 262144;   // 2048*512/4
  const long long NB4 = 512;      // 2048/4
  long long idx0 = (long long)blockIdx.x * blockDim.x + threadIdx.x;
  long long stride = (long long)gridDim.x * blockDim.x;
  // invalidate h tag slots (2 parities x 64 rows x 256 slots)
  for (long long u = idx0; u < 32768; u += stride)
    hbuf[u] = 0xFFFFFFFF00000000ull;
  for (long long u = idx0; u < NU4 + NB4; u += stride) {
    if (u < NU4) {
      int e = (int)(u << 2);
      int n = e >> 9, k = e & 511;
      float4 v = *(const float4*)(Us[n >> 9] + (size_t)(n & 511) * 512 + k);
      ((unsigned long long*)Uall)[u] = pack4(v);
    } else {
      long long q = u - NU4;
      int e = (int)(q << 2);
      int gate = e >> 9, r = e & 511;
      float4 a = *(const float4*)(bWs[gate] + r);
      float4 b = *(const float4*)(bUs[gate] + r);
      float4 sv;
      sv.x = a.x + b.x; sv.y = a.y + b.y; sv.z = a.z + b.z; sv.w = a.w + b.w;
      *(float4*)(ball + e) = sv;
    }
  }
}

// ------------------------------ Phase B ------------------------------------
// xw[m][n] = sum_k x[m][k]*W[n][k] + ball[n],  M=32768 N=2048 K=256.
// 128x128 tile, BK=64. Both A (x) and B (W gate) converted f32->bf16 inline.
__global__ __launch_bounds__(256, 2) void xw_gemm(
    const float* __restrict__ x,
    const float* __restrict__ Wf, const float* __restrict__ Wi,
    const float* __restrict__ Wo, const float* __restrict__ Wc,
    const float* __restrict__ ball,
    unsigned short* __restrict__ xw)
{
  __shared__ short As[128 * 72];
  __shared__ short Bs[128 * 72];
  const int tid = threadIdx.x;
  const int bn = blockIdx.x, bm = blockIdx.y;
  const int Mbase = bm * 128, Nbase = bn * 128;
  const int w = tid >> 6, L = tid & 63, lq = L >> 4, lr = L & 15;
  const int wm = w >> 1, wn = w & 1;
  const int srow = tid >> 1, shalf = tid & 1;

  const int gate = bn >> 2;   // 512-wide gates, 4 blocks each
  const float* Wg = gate == 0 ? Wf : gate == 1 ? Wi : gate == 2 ? Wo : Wc;
  const int nrow = (bn & 3) * 128 + srow;

  float4v acc[4][4];
  #pragma unroll
  for (int a = 0; a < 4; ++a)
    #pragma unroll
    for (int b = 0; b < 4; ++b) acc[a][b] = (float4v){0.f, 0.f, 0.f, 0.f};

  for (int ko = 0; ko < 256; ko += 64) {
    const float* gaf = x + (size_t)(Mbase + srow) * 256 + ko + shalf * 32;
    float4 fa[8];
    #pragma unroll
    for (int i = 0; i < 8; ++i) fa[i] = *(const float4*)(gaf + 4 * i);
    const float* gbf = Wg + (size_t)nrow * 256 + ko + shalf * 32;
    float4 fb[8];
    #pragma unroll
    for (int i = 0; i < 8; ++i) fb[i] = *(const float4*)(gbf + 4 * i);
    __syncthreads();  // protect previous iteration's LDS reads
    {
      unsigned long long* pa = (unsigned long long*)&As[srow * 72 + shalf * 32];
      unsigned long long* pb = (unsigned long long*)&Bs[srow * 72 + shalf * 32];
      #pragma unroll
      for (int i = 0; i < 8; ++i) { pa[i] = pack4(fa[i]); pb[i] = pack4(fb[i]); }
    }
    __syncthreads();
    #pragma unroll
    for (int kk = 0; kk < 64; kk += 32) {
      short8 af[4], bfr[4];
      #pragma unroll
      for (int mi = 0; mi < 4; ++mi)
        af[mi] = *(const short8*)&As[(wm * 64 + mi * 16 + lr) * 72 + kk + lq * 8];
      #pragma unroll
      for (int ni = 0; ni < 4; ++ni)
        bfr[ni] = *(const short8*)&Bs[(wn * 64 + ni * 16 + lr) * 72 + kk + lq * 8];
      #pragma unroll
      for (int mi = 0; mi < 4; ++mi)
        #pragma unroll
        for (int ni = 0; ni < 4; ++ni)
          acc[mi][ni] = __builtin_amdgcn_mfma_f32_16x16x32_bf16(
              af[mi], bfr[ni], acc[mi][ni], 0, 0, 0);
    }
  }
  #pragma unroll
  for (int ni = 0; ni < 4; ++ni) {
    int col = Nbase + wn * 64 + ni * 16 + lr;
    float bias = ball[col];
    #pragma unroll
    for (int mi = 0; mi < 4; ++mi) {
      #pragma unroll
      for (int r = 0; r < 4; ++r) {
        int row = Mbase + wm * 64 + mi * 16 + lq * 4 + r;
        xw[(size_t)row * 2048 + col] = f2bf(acc[mi][ni][r] + bias);
      }
    }
  }
}

// ------------------------------ Phase C ------------------------------------
// 128 WGs: g = wg>>5 (16 batch rows), s = wg&31 (16 hidden cols).
// Wave w = gate w. Lane(q = L>>4, n = L&15): MFMA m-index = n (U row within
// the wave's 16), C gives batch col = n, gate-col rows q*4..+4.
__global__ __launch_bounds__(256, 1) void lstm_scan(
    const unsigned short* __restrict__ xw,
    const unsigned short* __restrict__ Uall,
    unsigned long long* __restrict__ hbuf,   // [2][64][256] tagged slots
    float* __restrict__ out)
{
  __shared__ __align__(16) short hstage[2][16 * 520];  // h_{t-1}, dbl-buffered
  __shared__ __align__(16) float gatesb[2][4][16][20]; // gate tiles (f32)

  const int tid = threadIdx.x;
  const int wg = blockIdx.x;
  const int g = wg >> 5;
  const int s = wg & 31;
  const int w = tid >> 6, L = tid & 63, q = L >> 4, n = L & 15;

  // poll/stage mapping: thread -> (row in group, 16 consecutive 8B slots)
  const int prow = tid >> 4;
  const int psb  = (tid & 15) * 16;    // slot base; covers cols psb*2..+32

  // elementwise mapping: thread -> one cell (batch b, col c within slice)
  const int eb = tid >> 4;
  const int ec = tid & 15;

  float* hseq = out;
  float* hfin = out + (size_t)512 * 64 * 512;
  float* cfin = hfin + (size_t)64 * 512;

  // --- U A-fragments: gate w, rows s*16+n, full K=512 -> 16 frags = 64 VGPR.
  // Loaded once; opaque asm pin prevents the allocator from re-sinking the
  // loads into the loop (R3 failure mode: per-step L2 re-stream of U).
  float4v ufv[16];
  #pragma unroll
  for (int kt = 0; kt < 16; ++kt)
    ufv[kt] = *(const float4v*)(Uall +
        (size_t)(w * 512 + s * 16 + n) * 512 + kt * 32 + q * 8);
  #pragma unroll
  for (int kt = 0; kt < 16; ++kt)
    asm volatile("" : "+v"(ufv[kt].x), "+v"(ufv[kt].y),
                      "+v"(ufv[kt].z), "+v"(ufv[kt].w));

  // xw register pipeline: lane's 4 gate-cols (8B) one step ahead
  ushort4 xcur, xnxt;
  xcur = *(const ushort4*)(xw + (size_t)(g * 16 + n) * 2048 +
                           w * 512 + s * 16 + q * 4);

  float c_ = 0.f, h_ = 0.f;

  for (int t = 0; t < 512; ++t) {
    const int p = t & 1;
    // issue xw prefetch for t+1 (off critical path)
    {
      int tn = (t + 1 < 512) ? (t + 1) : 511;
      xnxt = *(const ushort4*)(xw + (size_t)(tn * 64 + g * 16 + n) * 2048 +
                               w * 512 + s * 16 + q * 4);
    }

    // acc init = xw tile (bias folded in Phase B)
    const unsigned short* xc = (const unsigned short*)&xcur;
    float4v a0 = {bf2f(xc[0]), bf2f(xc[1]), bf2f(xc[2]), bf2f(xc[3])};
    float4v a1 = {0.f, 0.f, 0.f, 0.f};

    if (t > 0) {
      // poll own tagged slots (self-validating: tag == t-1)
      const unsigned long long* src = hbuf +
          (size_t)((t - 1) & 1) * 16384 + (size_t)(g * 16 + prow) * 256 + psb;
      unsigned long long v[16];
      for (;;) {
        #pragma unroll
        for (int i = 0; i < 16; ++i)
          v[i] = __hip_atomic_load(&src[i], __ATOMIC_RELAXED,
                                   __HIP_MEMORY_SCOPE_AGENT);
        unsigned bad = 0;
        #pragma unroll
        for (int i = 0; i < 16; ++i)
          bad |= ((unsigned)(v[i] >> 32)) ^ (unsigned)(t - 1);
        if (!bad) break;
        __builtin_amdgcn_s_sleep(1);
      }
      // stage payloads -> hstage[p] (64B contiguous per thread)
      uint4v* dst4 = (uint4v*)((char*)&hstage[p][0] + prow * 1040 + psb * 4);
      #pragma unroll
      for (int j = 0; j < 4; ++j) {
        uint4v pk;
        pk.x = (unsigned)v[4 * j + 0];
        pk.y = (unsigned)v[4 * j + 1];
        pk.z = (unsigned)v[4 * j + 2];
        pk.w = (unsigned)v[4 * j + 3];
        dst4[j] = pk;
      }
      barrier_lds();  // B1: hstage[p] visible to all waves
      // B-frags: h[batch = n][k = kt*32 + q*8 ..+8]; 2 indep chains of 8
      #pragma unroll
      for (int kt = 0; kt < 8; ++kt) {
        short8 hbA = *(const short8*)&hstage[p][n * 520 + kt * 32 + q * 8];
        short8 hbB = *(const short8*)&hstage[p][n * 520 + (kt + 8) * 32 + q * 8];
        a0 = __builtin_amdgcn_mfma_f32_16x16x32_bf16(
            __builtin_bit_cast(short8, ufv[kt]), hbA, a0, 0, 0, 0);
        a1 = __builtin_amdgcn_mfma_f32_16x16x32_bf16(
            __builtin_bit_cast(short8, ufv[kt + 8]), hbB, a1, 0, 0, 0);
      }
    } else {
      barrier_lds();  // keep barrier count uniform-ish (t==0 only)
    }
    float4v acc = a0 + a1;

    // gate tile -> LDS: lane(q,n) owns gate w, batch n, cols q*4..+4
    *(float4v*)&gatesb[p][w][n][q * 4] = acc;
    barrier_lds();  // B2: gates visible

    // elementwise: thread owns (batch eb, col ec)
    float gf = gatesb[p][0][eb][ec];
    float gi = gatesb[p][1][eb][ec];
    float go = gatesb[p][2][eb][ec];
    float gc = gatesb[p][3][eb][ec];
    float f_ = 1.f / (1.f + __expf(-gf));
    float i_ = 1.f / (1.f + __expf(-gi));
    float o_ = 1.f / (1.f + __expf(-go));
    float ct = 1.f - 2.f / (__expf(2.f * gc) + 1.f);
    c_ = f_ * c_ + i_ * ct;
    h_ = o_ * (1.f - 2.f / (__expf(2.f * c_) + 1.f));

    // hseq out (nontemporal 4B; 16 consecutive threads = 64B line)
    size_t orow = (size_t)(t * 64 + g * 16 + eb) * 512 + s * 16 + ec;
    __builtin_nontemporal_store(h_, hseq + orow);

    // tagged handoff: even-col thread packs (h_even, h_odd) + tag
    float hodd = __shfl_xor(h_, 1);
    if (!(tid & 1)) {
      unsigned long long sv = (((unsigned long long)(unsigned)t) << 32) |
          (((unsigned long long)f2bf(hodd) << 16) | (unsigned)f2bf(h_));
      unsigned long long* dst = hbuf + (size_t)p * 16384 +
          (size_t)(g * 16 + eb) * 256 + s * 8 + (ec >> 1);
      __hip_atomic_store(dst, sv, __ATOMIC_RELAXED, __HIP_MEMORY_SCOPE_AGENT);
    }

    if (t == 511) {
      size_t fo = (size_t)(g * 16 + eb) * 512 + s * 16 + ec;
      hfin[fo] = h_;
      cfin[fo] = c_;
    }
    xcur = xnxt;
  }
}

// ------------------------------ launch -------------------------------------
extern "C" void kernel_launch(void* const* d_in, const int* in_sizes, int n_in,
                              void* d_out, int out_size, void* d_ws, size_t ws_size,
                              hipStream_t stream) {
  (void)in_sizes; (void)n_in; (void)out_size; (void)ws_size;
  const float* x   = (const float*)d_in[0];
  const float* Wf  = (const float*)d_in[1];
  const float* bWf = (const float*)d_in[2];
  const float* Wi  = (const float*)d_in[3];
  const float* bWi = (const float*)d_in[4];
  const float* Wo  = (const float*)d_in[5];
  const float* bWo = (const float*)d_in[6];
  const float* Wc  = (const float*)d_in[7];
  const float* bWc = (const float*)d_in[8];
  const float* Uf  = (const float*)d_in[9];
  const float* bUf = (const float*)d_in[10];
  const float* Ui  = (const float*)d_in[11];
  const float* bUi = (const float*)d_in[12];
  const float* Uo  = (const float*)d_in[13];
  const float* bUo = (const float*)d_in[14];
  const float* Uc  = (const float*)d_in[15];
  const float* bUc = (const float*)d_in[16];

  char* ws = (char*)d_ws;
  unsigned short*     xw   = (unsigned short*)(ws);              // 134217728 B
  unsigned short*     Uall = (unsigned short*)(ws + 134217728);  //   2097152 B
  float*              ball = (float*)         (ws + 136314880);  //      8192 B
  unsigned long long* hbuf = (unsigned long long*)(ws + 136323072); // 262144 B

  prep_kernel<<<512, 256, 0, stream>>>(Uf, bUf, Ui, bUi, Uo, bUo, Uc, bUc,
                                       bWf, bWi, bWo, bWc, Uall, ball, hbuf);
  xw_gemm<<<dim3(16, 256), 256, 0, stream>>>(x, Wf, Wi, Wo, Wc, ball, xw);
  lstm_scan<<<128, 256, 0, stream>>>(xw, Uall, hbuf, (float*)d_out);
}